// Round 5
// baseline (837.046 us; speedup 1.0000x reference)
//
#include <hip/hip_runtime.h>
#include <math.h>
#include <float.h>

// Problem constants
#define BATCH 16
#define CHN   256
#define HH    32
#define WW    32
#define NTOK  (BATCH*HH*WW)   // 16384 tokens
#define DIMS  256             // embedding dim
#define KCODES 8192           // codebook entries

// Argmin tiling
#define MBLK 128                          // tokens per block (4 waves x 32)
#define NSPLIT 4                          // grid = 128*4 = 512 blocks (2/CU)
#define CODES_PER_SPLIT (KCODES/NSPLIT)   // 2048
#define CCHUNK 64                         // codes per chunk
#define NCHUNKS (CODES_PER_SPLIT/CCHUNK)  // 32
#define NSTAGE  (NCHUNKS*4)               // 128 stage-steps (4 per chunk)
#define BROW 512                          // packed B row length in f16 (Bh|Bl)
#define BTSTR 136                         // LDS B row stride in f16 (128+8 pad)

#define GATHER_BLOCKS 4096

// Workspace layout (bytes) — same as round 1 (proven OK)
#define WS_CB2   0
#define WS_BESTV (32768)
#define WS_BESTI (WS_BESTV + NSPLIT*NTOK*4)
#define WS_IDX   (WS_BESTI + NSPLIT*NTOK*4)
#define WS_PART  (WS_IDX + NTOK*4)

typedef _Float16 f16;
typedef f16 f16x8 __attribute__((ext_vector_type(8)));
typedef float f32x4 __attribute__((ext_vector_type(4)));

// ---------------------------------------------------------------------------
// Kernel 1: cb2[k] = sum_d codebook[k][d]^2 (fp32, unscaled). One wave per row.
__global__ void cb2_kernel(const float* __restrict__ codebook, float* __restrict__ cb2) {
    int wv   = threadIdx.x >> 6;
    int lane = threadIdx.x & 63;
    int row  = blockIdx.x * 4 + wv;
    const float4 v = *(const float4*)&codebook[(size_t)row * DIMS + lane * 4];
    float s = v.x*v.x + v.y*v.y + v.z*v.z + v.w*v.w;
    #pragma unroll
    for (int m = 32; m >= 1; m >>= 1) s += __shfl_xor(s, m, 64);
    if (lane == 0) cb2[row] = s;
}

// ---------------------------------------------------------------------------
// Kernel 2: pack codebook into f16 limb planes: row[0:256]=Bh, [256:512]=Bl.
// Scaled x256 (argmin-invariant; keeps Bl out of f16-subnormal range).
__global__ void bpack_kernel(const float* __restrict__ codebook, f16* __restrict__ bpp) {
    int code = blockIdx.x;
    int k = threadIdx.x;
    float x = codebook[(size_t)code * DIMS + k] * 256.0f;
    f16 h = (f16)x;
    f16 l = (f16)(x - (float)h);
    f16* row = bpp + (size_t)code * BROW;
    row[k] = h;
    row[256 + k] = l;
}

// ---------------------------------------------------------------------------
// Kernel 3: MFMA distance-GEMM + running argmin (3-pass f16 limb split:
// dot ~= Ah*Bh + Al*Bh + Ah*Bl, fp32 accumulate).
// 4 waves x 32 tokens (mf=2): one B fragment read feeds 4 MFMAs -> device
// LDS-read demand ~4.3 GB (~55us), below the 99us MFMA floor.
// Single LDS buffer, two barriers per step; next step's global loads are
// prefetched into registers during compute (T14).
__global__ __launch_bounds__(256, 2) void argmin_kernel(
    const float* __restrict__ latent, const f16* __restrict__ bpp,
    const float* __restrict__ cb2,
    float* __restrict__ bestv_ws, int* __restrict__ besti_ws)
{
    __shared__ f16 Bt[CCHUNK * BTSTR];    // 64 x 136 f16 = 17408 B

    const int tid = threadIdx.x;
    const int wv = tid >> 6, l = tid & 63;
    const int bm = blockIdx.x >> 2;        // token block 0..127
    const int js = blockIdx.x & 3;         // code split 0..3 (== blockIdx%4 ->
                                           // each XCD sees one js: B panel L2-resident)
    const int n0 = bm * MBLK;
    const int bb = n0 >> 10, hw0 = n0 & 1023;
    const int code_base = js * CODES_PER_SPLIT;

    // ---- A prologue: direct global->register limb fragments (mf=2).
    // Wave wv owns tokens n0 + wv*32 + mfi*16 + (l&15); l>>4 = k-block;
    // fragment reg j -> k = kst*32 + (l>>4)*8 + j.
    f16x8 Ah[2][8], Al[2][8];
    #pragma unroll
    for (int mfi = 0; mfi < 2; ++mfi) {
        const float* latb = latent + (size_t)bb * (CHN*HH*WW) + hw0
                          + wv*32 + mfi*16 + (l & 15);
        #pragma unroll
        for (int kst = 0; kst < 8; ++kst) {
            f16x8 h, lo;
            #pragma unroll
            for (int j = 0; j < 8; ++j) {
                float v = latb[(size_t)(kst*32 + ((l >> 4) << 3) + j) * (HH*WW)];
                f16 hh = (f16)v;
                h[j] = hh;
                lo[j] = (f16)(v - (float)hh);
            }
            Ah[mfi][kst] = h;
            Al[mfi][kst] = lo;
        }
    }

    f32x4 acc[2][4];
    float bv[2][4];
    int   bi[2][4];
    #pragma unroll
    for (int mfi = 0; mfi < 2; ++mfi)
    #pragma unroll
    for (int nf = 0; nf < 4; ++nf) acc[mfi][nf] = (f32x4)0.0f;
    #pragma unroll
    for (int mfi = 0; mfi < 2; ++mfi)
    #pragma unroll
    for (int r = 0; r < 4; ++r) { bv[mfi][r] = FLT_MAX; bi[mfi][r] = 0x7fffffff; }

    // staging map (256 threads cover 64 rows x 16 slots, 4 float4/thread):
    // rows srow, srow+32; slots s8, s8+8. 8 consecutive lanes = 128B contiguous.
    const int srow = tid >> 3;             // 0..31
    const int s8   = tid & 7;              // 0..7

    float4 stg0, stg1, stg2, stg3;
    {   // prologue: load step 0 (chunk 0, sidx 0)
        const f16* p = bpp + (size_t)(code_base + srow) * BROW + s8*8;
        stg0 = *(const float4*)p;
        stg1 = *(const float4*)(p + 64);
        stg2 = *(const float4*)(p + (size_t)32*BROW);
        stg3 = *(const float4*)(p + (size_t)32*BROW + 64);
    }

    for (int t = 0; t < NSTAGE; ++t) {
        const int chunk = t >> 2;
        const int sidx  = t & 3;   // 0,1: Bh k-windows (Ah+Al passes); 2,3: Bl (Ah only)

        __syncthreads();           // prior step's compute done -> Bt free
        *(float4*)&Bt[srow*BTSTR + s8*8]          = stg0;
        *(float4*)&Bt[srow*BTSTR + (s8+8)*8]      = stg1;
        *(float4*)&Bt[(srow+32)*BTSTR + s8*8]     = stg2;
        *(float4*)&Bt[(srow+32)*BTSTR + (s8+8)*8] = stg3;
        __syncthreads();

        if (t + 1 < NSTAGE) {      // prefetch next step (latency hidden by MFMAs)
            const int nc = (t+1) >> 2, ns = (t+1) & 3;
            const f16* p = bpp + (size_t)(code_base + nc*CCHUNK + srow) * BROW
                         + ns*128 + s8*8;
            stg0 = *(const float4*)p;
            stg1 = *(const float4*)(p + 64);
            stg2 = *(const float4*)(p + (size_t)32*BROW);
            stg3 = *(const float4*)(p + (size_t)32*BROW + 64);
        }

        const int kb4 = (sidx & 1) * 4;
        #pragma unroll
        for (int ksub = 0; ksub < 4; ++ksub) {
            const int kst = kb4 + ksub;
            #pragma unroll
            for (int nf = 0; nf < 4; ++nf) {
                const f16x8 bf = *(const f16x8*)&Bt[(nf*16 + (l & 15))*BTSTR
                                                    + (ksub*4 + (l >> 4))*8];
                acc[0][nf] = __builtin_amdgcn_mfma_f32_16x16x32_f16(Ah[0][kst], bf, acc[0][nf], 0, 0, 0);
                acc[1][nf] = __builtin_amdgcn_mfma_f32_16x16x32_f16(Ah[1][kst], bf, acc[1][nf], 0, 0, 0);
                if (sidx < 2) {
                    acc[0][nf] = __builtin_amdgcn_mfma_f32_16x16x32_f16(Al[0][kst], bf, acc[0][nf], 0, 0, 0);
                    acc[1][nf] = __builtin_amdgcn_mfma_f32_16x16x32_f16(Al[1][kst], bf, acc[1][nf], 0, 0, 0);
                }
            }
        }

        if (sidx == 3) {
            // fold chunk scores (codes ascend per lane -> strict '<' == np.argmin)
            const int code0 = code_base + chunk*CCHUNK;
            #pragma unroll
            for (int nf = 0; nf < 4; ++nf) {
                const int code = code0 + nf*16 + (l & 15);
                const float c2 = cb2[code];
                #pragma unroll
                for (int mfi = 0; mfi < 2; ++mfi)
                #pragma unroll
                for (int r = 0; r < 4; ++r) {
                    float v = fmaf(acc[mfi][nf][r], -0.0078125f, c2);  // c2 - 2*dot
                    if (v < bv[mfi][r]) { bv[mfi][r] = v; bi[mfi][r] = code; }
                    acc[mfi][nf][r] = 0.0f;
                }
            }
        }
    }

    // ---- reduce across the 16 code-lanes; write per-token best ----
    #pragma unroll
    for (int mfi = 0; mfi < 2; ++mfi)
    #pragma unroll
    for (int r = 0; r < 4; ++r) {
        float v = bv[mfi][r];
        int ix = bi[mfi][r];
        #pragma unroll
        for (int m = 1; m <= 8; m <<= 1) {
            float ov = __shfl_xor(v, m, 64);
            int   oi = __shfl_xor(ix, m, 64);
            if (ov < v || (ov == v && oi < ix)) { v = ov; ix = oi; }
        }
        if ((l & 15) == 0) {
            int tt = n0 + wv*32 + mfi*16 + ((l >> 4) << 2) + r;  // D row=(l>>4)*4+r
            bestv_ws[js*NTOK + tt] = v;
            besti_ws[js*NTOK + tt] = ix;
        }
    }
}

// ---------------------------------------------------------------------------
// Kernel 4: combine the NSPLIT partial argmins per token.
__global__ void combine_kernel(const float* __restrict__ bestv_ws,
                               const int* __restrict__ besti_ws,
                               int* __restrict__ idx_ws)
{
    int n = blockIdx.x * 256 + threadIdx.x;
    float v = bestv_ws[n];
    int  ix = besti_ws[n];
    #pragma unroll
    for (int js = 1; js < NSPLIT; ++js) {
        float ov = bestv_ws[js * NTOK + n];
        int   oi = besti_ws[js * NTOK + n];
        if (ov < v || (ov == v && oi < ix)) { v = ov; ix = oi; }
    }
    idx_ws[n] = ix;
}

// ---------------------------------------------------------------------------
// Kernel 5: gather codebook rows -> quantized output (NCHW), loss partials.
__global__ __launch_bounds__(256) void gather_kernel(
    const float* __restrict__ latent, const float* __restrict__ codebook,
    const int* __restrict__ idx_ws, float* __restrict__ out,
    float* __restrict__ partials)
{
    int gid = blockIdx.x * 256 + threadIdx.x;
    int o = gid * 4;                       // flat NCHW index, 4 consecutive w
    int w0 = o & 31;
    int h  = (o >> 5) & 31;
    int c  = (o >> 10) & 255;
    int b  = o >> 18;
    int nb = (b << 10) + (h << 5) + w0;    // token index of first element

    float4 x = *(const float4*)&latent[o];
    float4 q;
    q.x = codebook[(size_t)idx_ws[nb + 0] * DIMS + c];
    q.y = codebook[(size_t)idx_ws[nb + 1] * DIMS + c];
    q.z = codebook[(size_t)idx_ws[nb + 2] * DIMS + c];
    q.w = codebook[(size_t)idx_ws[nb + 3] * DIMS + c];
    *(float4*)&out[o] = q;

    float dx = q.x - x.x, dy = q.y - x.y, dz = q.z - x.z, dw = q.w - x.w;
    float s = dx*dx + dy*dy + dz*dz + dw*dw;
    #pragma unroll
    for (int m = 32; m >= 1; m >>= 1) s += __shfl_xor(s, m, 64);

    __shared__ float wsum[4];
    int lane = threadIdx.x & 63, wv = threadIdx.x >> 6;
    if (lane == 0) wsum[wv] = s;
    __syncthreads();
    if (threadIdx.x == 0)
        partials[blockIdx.x] = wsum[0] + wsum[1] + wsum[2] + wsum[3];
}

// ---------------------------------------------------------------------------
// Kernel 6: final loss reduction (double accumulate), write both scalars.
__global__ void loss_kernel(const float* __restrict__ partials, float* __restrict__ out) {
    __shared__ double sd[256];
    double s = 0.0;
    #pragma unroll
    for (int r = 0; r < GATHER_BLOCKS / 256; ++r)
        s += (double)partials[threadIdx.x + r * 256];
    sd[threadIdx.x] = s;
    __syncthreads();
    for (int k = 128; k >= 1; k >>= 1) {
        if (threadIdx.x < k) sd[threadIdx.x] += sd[threadIdx.x + k];
        __syncthreads();
    }
    if (threadIdx.x == 0) {
        float loss = (float)(sd[0] / (double)((size_t)NTOK * DIMS));
        out[(size_t)NTOK * DIMS + 0] = loss;  // codebook_loss
        out[(size_t)NTOK * DIMS + 1] = loss;  // commitment_loss (same fwd value)
    }
}

// ---------------------------------------------------------------------------
extern "C" void kernel_launch(void* const* d_in, const int* in_sizes, int n_in,
                              void* d_out, int out_size, void* d_ws, size_t ws_size,
                              hipStream_t stream) {
    (void)in_sizes; (void)n_in; (void)out_size; (void)ws_size;
    const float* latent   = (const float*)d_in[0];
    const float* codebook = (const float*)d_in[1];
    float* out = (float*)d_out;
    char*  ws  = (char*)d_ws;

    float* cb2   = (float*)(ws + WS_CB2);
    float* bestv = (float*)(ws + WS_BESTV);
    int*   besti = (int*)(ws + WS_BESTI);
    int*   idx   = (int*)(ws + WS_IDX);
    float* part  = (float*)(ws + WS_PART);

    // B limb planes live in d_out scratch (8.39 MB < 16.78 MB); the gather
    // kernel fully overwrites d_out afterwards.
    f16* bpp = (f16*)d_out;

    cb2_kernel<<<KCODES / 4, 256, 0, stream>>>(codebook, cb2);
    bpack_kernel<<<KCODES, 256, 0, stream>>>(codebook, bpp);
    argmin_kernel<<<(NTOK / MBLK) * NSPLIT, 256, 0, stream>>>(latent, bpp, cb2, bestv, besti);
    combine_kernel<<<NTOK / 256, 256, 0, stream>>>(bestv, besti, idx);
    gather_kernel<<<GATHER_BLOCKS, 256, 0, stream>>>(latent, codebook, idx, out, part);
    loss_kernel<<<1, 256, 0, stream>>>(part, out);
}

// Round 6
// 224.431 us; speedup vs baseline: 3.7296x; 3.7296x over previous
//
#include <hip/hip_runtime.h>
#include <math.h>
#include <float.h>

// Problem constants
#define BATCH 16
#define CHN   256
#define HH    32
#define WW    32
#define NTOK  (BATCH*HH*WW)   // 16384 tokens
#define DIMS  256             // embedding dim
#define KCODES 8192           // codebook entries

// Argmin tiling
#define MBLK 128                          // tokens per block (4 waves x 32)
#define NSPLIT 4                          // grid = 128*4 = 512 blocks (2/CU)
#define CODES_PER_SPLIT (KCODES/NSPLIT)   // 2048
#define CCHUNK 64                         // codes per chunk
#define NCHUNKS (CODES_PER_SPLIT/CCHUNK)  // 32
#define BROW 512                          // packed B row length in f16 (Bh|Bl)
#define BTSTR 136                         // LDS B row stride in f16 (128+8 pad)

#define GATHER_BLOCKS 4096

// Workspace layout (bytes) — same as round 1 (proven OK)
#define WS_CB2   0
#define WS_BESTV (32768)
#define WS_BESTI (WS_BESTV + NSPLIT*NTOK*4)
#define WS_IDX   (WS_BESTI + NSPLIT*NTOK*4)
#define WS_PART  (WS_IDX + NTOK*4)

typedef _Float16 f16;
typedef f16 f16x8 __attribute__((ext_vector_type(8)));
typedef float f32x4 __attribute__((ext_vector_type(4)));

// ---------------------------------------------------------------------------
// Kernel 1: cb2[k] = sum_d codebook[k][d]^2 (fp32, unscaled). One wave per row.
__global__ void cb2_kernel(const float* __restrict__ codebook, float* __restrict__ cb2) {
    int wv   = threadIdx.x >> 6;
    int lane = threadIdx.x & 63;
    int row  = blockIdx.x * 4 + wv;
    const float4 v = *(const float4*)&codebook[(size_t)row * DIMS + lane * 4];
    float s = v.x*v.x + v.y*v.y + v.z*v.z + v.w*v.w;
    #pragma unroll
    for (int m = 32; m >= 1; m >>= 1) s += __shfl_xor(s, m, 64);
    if (lane == 0) cb2[row] = s;
}

// ---------------------------------------------------------------------------
// Kernel 2: pack codebook into f16 limb planes: row[0:256]=Bh, [256:512]=Bl.
// Scaled x256 (argmin-invariant; keeps Bl out of f16-subnormal range).
__global__ void bpack_kernel(const float* __restrict__ codebook, f16* __restrict__ bpp) {
    int code = blockIdx.x;
    int k = threadIdx.x;
    float x = codebook[(size_t)code * DIMS + k] * 256.0f;
    f16 h = (f16)x;
    f16 l = (f16)(x - (float)h);
    f16* row = bpp + (size_t)code * BROW;
    row[k] = h;
    row[256 + k] = l;
}

// ---------------------------------------------------------------------------
// Kernel 3: MFMA distance-GEMM + running argmin (3-pass f16 limb split:
// dot ~= Ah*Bh + Al*Bh + Ah*Bl, fp32 accumulate).
// 4 waves x 32 tokens (mf=2): one B fragment read feeds 4 MFMAs.
// sidx is a fully-unrolled compile-time loop index so the A-fragment arrays
// stay register-resident (rule #20: runtime indexing -> scratch, the round-5
// regression). Single LDS buffer, two barriers per step; next step's global
// loads prefetched into registers during compute (T14).
__global__ __launch_bounds__(256, 2) void argmin_kernel(
    const float* __restrict__ latent, const f16* __restrict__ bpp,
    const float* __restrict__ cb2,
    float* __restrict__ bestv_ws, int* __restrict__ besti_ws)
{
    __shared__ f16 Bt[CCHUNK * BTSTR];    // 64 x 136 f16 = 17408 B

    const int tid = threadIdx.x;
    const int wv = tid >> 6, l = tid & 63;
    const int bm = blockIdx.x >> 2;        // token block 0..127
    const int js = blockIdx.x & 3;         // code split 0..3 (blockIdx%8 round-robin
                                           // pins each XCD to one js: B panel L2-resident)
    const int n0 = bm * MBLK;
    const int bb = n0 >> 10, hw0 = n0 & 1023;
    const int code_base = js * CODES_PER_SPLIT;

    // ---- A prologue: direct global->register limb fragments (mf=2).
    // Wave wv owns tokens n0 + wv*32 + mfi*16 + (l&15); l>>4 = k-block;
    // fragment reg j -> k = kst*32 + (l>>4)*8 + j.
    f16x8 Ah[2][8], Al[2][8];
    #pragma unroll
    for (int mfi = 0; mfi < 2; ++mfi) {
        const float* latb = latent + (size_t)bb * (CHN*HH*WW) + hw0
                          + wv*32 + mfi*16 + (l & 15);
        #pragma unroll
        for (int kst = 0; kst < 8; ++kst) {
            f16x8 h, lo;
            #pragma unroll
            for (int j = 0; j < 8; ++j) {
                float v = latb[(size_t)(kst*32 + ((l >> 4) << 3) + j) * (HH*WW)];
                f16 hh = (f16)v;
                h[j] = hh;
                lo[j] = (f16)(v - (float)hh);
            }
            Ah[mfi][kst] = h;
            Al[mfi][kst] = lo;
        }
    }

    f32x4 acc[2][4];
    float bv[2][4];
    int   bi[2][4];
    #pragma unroll
    for (int mfi = 0; mfi < 2; ++mfi)
    #pragma unroll
    for (int nf = 0; nf < 4; ++nf) acc[mfi][nf] = (f32x4)0.0f;
    #pragma unroll
    for (int mfi = 0; mfi < 2; ++mfi)
    #pragma unroll
    for (int r = 0; r < 4; ++r) { bv[mfi][r] = FLT_MAX; bi[mfi][r] = 0x7fffffff; }

    // staging map (256 threads cover 64 rows x 16 slots, 4 float4/thread):
    // rows srow, srow+32; slots s8, s8+8. 8 consecutive lanes = 128B contiguous.
    const int srow = tid >> 3;             // 0..31
    const int s8   = tid & 7;              // 0..7

    float4 stg0, stg1, stg2, stg3;
    {   // prologue: load step 0 (chunk 0, sidx 0)
        const f16* p = bpp + (size_t)(code_base + srow) * BROW + s8*8;
        stg0 = *(const float4*)p;
        stg1 = *(const float4*)(p + 64);
        stg2 = *(const float4*)(p + (size_t)32*BROW);
        stg3 = *(const float4*)(p + (size_t)32*BROW + 64);
    }

    for (int chunk = 0; chunk < NCHUNKS; ++chunk) {
        #pragma unroll
        for (int sidx = 0; sidx < 4; ++sidx) {
            // sidx 0,1: Bh k-windows [0:128),[128:256) -> Ah AND Al passes
            // sidx 2,3: Bl k-windows                   -> Ah pass only
            __syncthreads();           // prior step's compute done -> Bt free
            *(float4*)&Bt[srow*BTSTR + s8*8]          = stg0;
            *(float4*)&Bt[srow*BTSTR + (s8+8)*8]      = stg1;
            *(float4*)&Bt[(srow+32)*BTSTR + s8*8]     = stg2;
            *(float4*)&Bt[(srow+32)*BTSTR + (s8+8)*8] = stg3;
            __syncthreads();

            // prefetch next step (latency hidden by MFMAs below)
            if (sidx < 3 || chunk + 1 < NCHUNKS) {
                const int nc = (sidx == 3) ? chunk + 1 : chunk;
                const int ns = (sidx + 1) & 3;
                const f16* p = bpp + (size_t)(code_base + nc*CCHUNK + srow) * BROW
                             + ns*128 + s8*8;
                stg0 = *(const float4*)p;
                stg1 = *(const float4*)(p + 64);
                stg2 = *(const float4*)(p + (size_t)32*BROW);
                stg3 = *(const float4*)(p + (size_t)32*BROW + 64);
            }

            const int kb4 = (sidx & 1) * 4;   // compile-time after unroll
            #pragma unroll
            for (int ksub = 0; ksub < 4; ++ksub) {
                const int kst = kb4 + ksub;   // compile-time
                #pragma unroll
                for (int nf = 0; nf < 4; ++nf) {
                    const f16x8 bf = *(const f16x8*)&Bt[(nf*16 + (l & 15))*BTSTR
                                                        + (ksub*4 + (l >> 4))*8];
                    acc[0][nf] = __builtin_amdgcn_mfma_f32_16x16x32_f16(Ah[0][kst], bf, acc[0][nf], 0, 0, 0);
                    acc[1][nf] = __builtin_amdgcn_mfma_f32_16x16x32_f16(Ah[1][kst], bf, acc[1][nf], 0, 0, 0);
                    if (sidx < 2) {
                        acc[0][nf] = __builtin_amdgcn_mfma_f32_16x16x32_f16(Al[0][kst], bf, acc[0][nf], 0, 0, 0);
                        acc[1][nf] = __builtin_amdgcn_mfma_f32_16x16x32_f16(Al[1][kst], bf, acc[1][nf], 0, 0, 0);
                    }
                }
            }

            if (sidx == 3) {
                // fold chunk scores (codes ascend per lane -> strict '<' == np.argmin)
                const int code0 = code_base + chunk*CCHUNK;
                #pragma unroll
                for (int nf = 0; nf < 4; ++nf) {
                    const int code = code0 + nf*16 + (l & 15);
                    const float c2 = cb2[code];
                    #pragma unroll
                    for (int mfi = 0; mfi < 2; ++mfi)
                    #pragma unroll
                    for (int r = 0; r < 4; ++r) {
                        float v = fmaf(acc[mfi][nf][r], -0.0078125f, c2);  // c2 - 2*dot
                        if (v < bv[mfi][r]) { bv[mfi][r] = v; bi[mfi][r] = code; }
                        acc[mfi][nf][r] = 0.0f;
                    }
                }
            }
        }
    }

    // ---- reduce across the 16 code-lanes; write per-token best ----
    #pragma unroll
    for (int mfi = 0; mfi < 2; ++mfi)
    #pragma unroll
    for (int r = 0; r < 4; ++r) {
        float v = bv[mfi][r];
        int ix = bi[mfi][r];
        #pragma unroll
        for (int m = 1; m <= 8; m <<= 1) {
            float ov = __shfl_xor(v, m, 64);
            int   oi = __shfl_xor(ix, m, 64);
            if (ov < v || (ov == v && oi < ix)) { v = ov; ix = oi; }
        }
        if ((l & 15) == 0) {
            int tt = n0 + wv*32 + mfi*16 + ((l >> 4) << 2) + r;  // D row=(l>>4)*4+r
            bestv_ws[js*NTOK + tt] = v;
            besti_ws[js*NTOK + tt] = ix;
        }
    }
}

// ---------------------------------------------------------------------------
// Kernel 4: combine the NSPLIT partial argmins per token.
__global__ void combine_kernel(const float* __restrict__ bestv_ws,
                               const int* __restrict__ besti_ws,
                               int* __restrict__ idx_ws)
{
    int n = blockIdx.x * 256 + threadIdx.x;
    float v = bestv_ws[n];
    int  ix = besti_ws[n];
    #pragma unroll
    for (int js = 1; js < NSPLIT; ++js) {
        float ov = bestv_ws[js * NTOK + n];
        int   oi = besti_ws[js * NTOK + n];
        if (ov < v || (ov == v && oi < ix)) { v = ov; ix = oi; }
    }
    idx_ws[n] = ix;
}

// ---------------------------------------------------------------------------
// Kernel 5: gather codebook rows -> quantized output (NCHW), loss partials.
__global__ __launch_bounds__(256) void gather_kernel(
    const float* __restrict__ latent, const float* __restrict__ codebook,
    const int* __restrict__ idx_ws, float* __restrict__ out,
    float* __restrict__ partials)
{
    int gid = blockIdx.x * 256 + threadIdx.x;
    int o = gid * 4;                       // flat NCHW index, 4 consecutive w
    int w0 = o & 31;
    int h  = (o >> 5) & 31;
    int c  = (o >> 10) & 255;
    int b  = o >> 18;
    int nb = (b << 10) + (h << 5) + w0;    // token index of first element

    float4 x = *(const float4*)&latent[o];
    float4 q;
    q.x = codebook[(size_t)idx_ws[nb + 0] * DIMS + c];
    q.y = codebook[(size_t)idx_ws[nb + 1] * DIMS + c];
    q.z = codebook[(size_t)idx_ws[nb + 2] * DIMS + c];
    q.w = codebook[(size_t)idx_ws[nb + 3] * DIMS + c];
    *(float4*)&out[o] = q;

    float dx = q.x - x.x, dy = q.y - x.y, dz = q.z - x.z, dw = q.w - x.w;
    float s = dx*dx + dy*dy + dz*dz + dw*dw;
    #pragma unroll
    for (int m = 32; m >= 1; m >>= 1) s += __shfl_xor(s, m, 64);

    __shared__ float wsum[4];
    int lane = threadIdx.x & 63, wv = threadIdx.x >> 6;
    if (lane == 0) wsum[wv] = s;
    __syncthreads();
    if (threadIdx.x == 0)
        partials[blockIdx.x] = wsum[0] + wsum[1] + wsum[2] + wsum[3];
}

// ---------------------------------------------------------------------------
// Kernel 6: final loss reduction (double accumulate), write both scalars.
__global__ void loss_kernel(const float* __restrict__ partials, float* __restrict__ out) {
    __shared__ double sd[256];
    double s = 0.0;
    #pragma unroll
    for (int r = 0; r < GATHER_BLOCKS / 256; ++r)
        s += (double)partials[threadIdx.x + r * 256];
    sd[threadIdx.x] = s;
    __syncthreads();
    for (int k = 128; k >= 1; k >>= 1) {
        if (threadIdx.x < k) sd[threadIdx.x] += sd[threadIdx.x + k];
        __syncthreads();
    }
    if (threadIdx.x == 0) {
        float loss = (float)(sd[0] / (double)((size_t)NTOK * DIMS));
        out[(size_t)NTOK * DIMS + 0] = loss;  // codebook_loss
        out[(size_t)NTOK * DIMS + 1] = loss;  // commitment_loss (same fwd value)
    }
}

// ---------------------------------------------------------------------------
extern "C" void kernel_launch(void* const* d_in, const int* in_sizes, int n_in,
                              void* d_out, int out_size, void* d_ws, size_t ws_size,
                              hipStream_t stream) {
    (void)in_sizes; (void)n_in; (void)out_size; (void)ws_size;
    const float* latent   = (const float*)d_in[0];
    const float* codebook = (const float*)d_in[1];
    float* out = (float*)d_out;
    char*  ws  = (char*)d_ws;

    float* cb2   = (float*)(ws + WS_CB2);
    float* bestv = (float*)(ws + WS_BESTV);
    int*   besti = (int*)(ws + WS_BESTI);
    int*   idx   = (int*)(ws + WS_IDX);
    float* part  = (float*)(ws + WS_PART);

    // B limb planes live in d_out scratch (8.39 MB < 16.78 MB); the gather
    // kernel fully overwrites d_out afterwards.
    f16* bpp = (f16*)d_out;

    cb2_kernel<<<KCODES / 4, 256, 0, stream>>>(codebook, cb2);
    bpack_kernel<<<KCODES, 256, 0, stream>>>(codebook, bpp);
    argmin_kernel<<<(NTOK / MBLK) * NSPLIT, 256, 0, stream>>>(latent, bpp, cb2, bestv, besti);
    combine_kernel<<<NTOK / 256, 256, 0, stream>>>(bestv, besti, idx);
    gather_kernel<<<GATHER_BLOCKS, 256, 0, stream>>>(latent, codebook, idx, out, part);
    loss_kernel<<<1, 256, 0, stream>>>(part, out);
}